// Round 6
// baseline (446.400 us; speedup 1.0000x reference)
//
#include <hip/hip_runtime.h>

#define N_PTS 8192
#define R2F 0.015625f   // R*R, exactly representable

// ---------------- g = x @ W1a (NO bias; R16 chain verbatim, 32-row tiles) ---
__global__ __launch_bounds__(256) void k_g(const float* __restrict__ x,
                                           const float* __restrict__ W1,
                                           float* __restrict__ g) {
    __shared__ float xs[32][68];
    __shared__ float ws_[64][64];
    const int t = threadIdx.x;
    const int r0 = blockIdx.x * 32;
    for (int v = t; v < 1024; v += 256)
        ((float4*)&ws_[0][0])[v] = ((const float4*)W1)[v];   // W1 rows 0..63
    for (int v = t; v < 512; v += 256) {
        const int n = v >> 4, c4 = (v & 15) * 4;
        *(float4*)&xs[n][c4] = *(const float4*)&x[(r0 + n) * 64 + c4];
    }
    __syncthreads();
    const int c0 = (t & 15) * 4, n0 = (t >> 4) * 2;
    float acc[2][4];
    #pragma unroll
    for (int ni = 0; ni < 2; ++ni)
        #pragma unroll
        for (int ci = 0; ci < 4; ++ci) acc[ni][ci] = 0.0f;
    #pragma unroll
    for (int kb4 = 0; kb4 < 16; ++kb4) {
        float4 av[2], wv[4];
        #pragma unroll
        for (int ni = 0; ni < 2; ++ni)
            av[ni] = *(const float4*)&xs[n0 + ni][kb4 * 4];
        #pragma unroll
        for (int ki = 0; ki < 4; ++ki)
            wv[ki] = *(const float4*)&ws_[kb4 * 4 + ki][c0];
        #pragma unroll
        for (int ki = 0; ki < 4; ++ki) {           // k = 4*kb4 + ki, ascending
            #pragma unroll
            for (int ni = 0; ni < 2; ++ni) {
                const float a = (&av[ni].x)[ki];
                acc[ni][0] = __fmaf_rn(a, wv[ki].x, acc[ni][0]);
                acc[ni][1] = __fmaf_rn(a, wv[ki].y, acc[ni][1]);
                acc[ni][2] = __fmaf_rn(a, wv[ki].z, acc[ni][2]);
                acc[ni][3] = __fmaf_rn(a, wv[ki].w, acc[ni][3]);
            }
        }
    }
    #pragma unroll
    for (int ni = 0; ni < 2; ++ni)
        *(float4*)&g[(r0 + n0 + ni) * 64 + c0] =
            make_float4(acc[ni][0], acc[ni][1], acc[ni][2], acc[ni][3]);
}

// ---------------- main fused kernel: TWO points per 512-thread block --------
// Half h (threads [256h, 256h+256)) processes point i = 2*blockIdx.x + h with
// the proven per-point pipeline verbatim (mechanical t -> (h, th) re-index).
// LDS ~39.9 KB -> 4 blocks/CU. __launch_bounds__(512, 4): second arg is
// min-BLOCKS-per-CU on this compiler (R4 evidence: (512,8) -> 16 waves/SIMD
// budget -> 32-VGPR cap -> kb[] spilled to scratch, 12x HBM traffic).
// 4 blocks * 8 waves / 4 SIMDs = 8 waves/SIMD -> 64-VGPR cap >= the ~60 needed.
union U0 {
    struct { unsigned mb[4][64]; unsigned mj[4][64]; } s;   // 2 KB
    float gs[64][68];                                       // 17408 B
};

__global__ __launch_bounds__(512, 4) void fused_all(const float* __restrict__ g,
                                                    const float* __restrict__ pos,
                                                    const float* __restrict__ W1,
                                                    const float* __restrict__ b1,
                                                    const float* __restrict__ W2,
                                                    const float* __restrict__ b2,
                                                    const float* __restrict__ Wg,
                                                    const float* __restrict__ bg,
                                                    float* __restrict__ out) {
    __shared__ U0       u0[2];        // 34816 B
    __shared__ float    pmw[2][4][128];  // 4 KB; pmw[h][0] doubles as agg
    __shared__ unsigned selb[2][64];
    __shared__ int      selj[2][64];
    __shared__ int      nvalidS[2];   // total ~39.9 KB -> 4 blocks/CU

    const int t    = threadIdx.x;     // 0..511
    const int h    = t >> 8;          // half / point sub-index
    const int th   = t & 255;         // thread-in-half, 0..255
    const int lane = th & 63;
    const int w    = th >> 6;         // wave-in-half; owns quarter [2048w, 2048w+2048)
    const int qb   = w << 11;
    const int i    = blockIdx.x * 2 + h;

    const float xi = pos[i * 3 + 0], yi = pos[i * 3 + 1], zi = pos[i * 3 + 2];
    const float sqi = __fadd_rn(__fadd_rn(__fmul_rn(xi, xi), __fmul_rn(yi, yi)),
                                __fmul_rn(zi, zi));

    // ---- phase 1: d2 keys; track per-lane two smallest (b, j) ----
    unsigned kb[32];
    unsigned m1b = 0xFFFFFFFFu, m2b = 0xFFFFFFFFu;
    int      m1j = 0x7FFFFFFF,  m2j = 0x7FFFFFFF;
    #pragma unroll
    for (int k = 0; k < 32; ++k) {
        const int j = qb + lane + (k << 6);
        const float xj = pos[j * 3 + 0], yj = pos[j * 3 + 1], zj = pos[j * 3 + 2];
        const float sqj = __fadd_rn(__fadd_rn(__fmul_rn(xj, xj), __fmul_rn(yj, yj)),
                                    __fmul_rn(zj, zj));
        const float dot = __fmaf_rn(zi, zj, __fmaf_rn(yi, yj, __fmul_rn(xi, xj)));
        const float d2  = __fsub_rn(__fadd_rn(sqi, sqj), __fmul_rn(2.0f, dot));
        unsigned b = __float_as_uint(d2);
        b = (b & 0x80000000u) ? ~b : (b | 0x80000000u);  // monotone total order
        kb[k] = b;
        // two-min update; j ascending, so on b-tie the incumbent (smaller j) wins
        if (b < m1b)      { m2b = m1b; m2j = m1j; m1b = b; m1j = j; }
        else if (b < m2b) { m2b = b;   m2j = j; }
    }

    // unique ascending pads: no rank collisions in the merge (the R9 bug)
    u0[h].s.mb[w][lane] = 0xFFFFFFFFu;
    u0[h].s.mj[w][lane] = 0xFFFFFF00u | (unsigned)((w << 6) | lane);

    // ---- pops with early exit; lazy lane-min: min1 -> min2 -> rescan ----
    unsigned removed = 0u;
    int      level = 0;
    unsigned lb = m1b;
    int      lj = m1j;
    for (int s = 0; s < 64; ++s) {
        unsigned rb = lb;
        int      rj = lj;
        #pragma unroll
        for (int off = 32; off > 0; off >>= 1) {
            const unsigned ob = (unsigned)__shfl_down((int)rb, off);
            const int      oj = __shfl_down(rj, off);
            if (ob < rb || (ob == rb && oj < rj)) { rb = ob; rj = oj; }
        }
        const unsigned wb = (unsigned)__shfl((int)rb, 0);
        const int      wj = __shfl(rj, 0);
        const unsigned db = (wb & 0x80000000u) ? (wb ^ 0x80000000u) : ~wb;
        if (!(__uint_as_float(db) <= R2F)) break;   // wave-uniform; pops ascend
        if (lane == 0) { u0[h].s.mb[w][s] = wb; u0[h].s.mj[w][s] = (unsigned)wj; }
        if (lb == wb && lj == wj) {                 // unique owner lane
            removed |= 1u << ((wj - qb - lane) >> 6);
            ++level;
            if (level == 1) { lb = m2b; lj = m2j; }
            else {                                  // rare (~3% of lanes)
                lb = 0xFFFFFFFFu; lj = 0x7FFFFFFF;
                #pragma unroll
                for (int k = 0; k < 32; ++k) {
                    if (!(removed & (1u << k))) {
                        const unsigned b = kb[k];
                        if (b < lb) { lb = b; lj = qb + lane + (k << 6); }
                    }
                }
            }
        }
    }
    __syncthreads();

    {   // merge: exact global top-64 by (b, j) via parallel rank (bijective)
        const int p = lane;
        const unsigned be = u0[h].s.mb[w][p];
        const unsigned je = u0[h].s.mj[w][p];
        int rank = p;
        #pragma unroll
        for (int d = 1; d < 4; ++d) {
            const int wp = (w + d) & 3;
            int lo = 0;
            #pragma unroll
            for (int st = 32; st > 0; st >>= 1) {
                const int idx = lo + st - 1;
                const unsigned ob = u0[h].s.mb[wp][idx];
                const unsigned oj = u0[h].s.mj[wp][idx];
                if (ob < be || (ob == be && oj < je)) lo += st;
            }
            {
                const unsigned ob = u0[h].s.mb[wp][lo];
                const unsigned oj = u0[h].s.mj[wp][lo];
                if (ob < be || (ob == be && oj < je)) lo += 1;
            }
            rank += lo;
        }
        if (rank < 64) { selb[h][rank] = be; selj[h][rank] = (int)(je & 8191u); }
    }
    __syncthreads();

    // ======== gather g rows (overwrites mb/mj), nvalid ballot ==============
    for (int v = th; v < 1024; v += 256) {
        const int n = v >> 4, c4 = (v & 15) * 4;   // rows >= nvalid never used
        *(float4*)&u0[h].gs[n][c4] = *(const float4*)&g[selj[h][n] * 64 + c4];
    }
    {
        bool ok = false;
        if (th < 64) {
            const unsigned b = selb[h][th];
            const unsigned db = (b & 0x80000000u) ? (b ^ 0x80000000u) : ~b;
            ok = (__uint_as_float(db) <= R2F);     // pads decode NaN -> false
        }
        const unsigned long long vm = __ballot(ok);  // per-wave; th<64 is one wave
        if (th == 0) nvalidS[h] = __popcll(vm);    // asc d2 -> popcount == prefix
    }
    __syncthreads();
    const int nvalid = nvalidS[h];

    // ======== phase 2: h1 = relu(g + rel @ W1b + b1), IN PLACE over gs ======
    {
        const int c0 = (th & 15) * 4, n0 = (th >> 4) * 4;
        float rr[4][3];
        #pragma unroll
        for (int ni = 0; ni < 4; ++ni) {
            const int j = selj[h][n0 + ni];
            rr[ni][0] = pos[j * 3 + 0] - xi;
            rr[ni][1] = pos[j * 3 + 1] - yi;
            rr[ni][2] = pos[j * 3 + 2] - zi;
        }
        float w1b[3][4], bb[4];
        #pragma unroll
        for (int ci = 0; ci < 4; ++ci) {
            w1b[0][ci] = W1[4096 + c0 + ci];
            w1b[1][ci] = W1[4160 + c0 + ci];
            w1b[2][ci] = W1[4224 + c0 + ci];
            bb[ci]     = b1[c0 + ci];
        }
        #pragma unroll
        for (int ni = 0; ni < 4; ++ni) {
            const int n = n0 + ni;
            const float4 gv = *(const float4*)&u0[h].gs[n][c0];
            float4 hv;
            #pragma unroll
            for (int ci = 0; ci < 4; ++ci) {
                float a = (&gv.x)[ci];             // == full ascending-k sum
                a = __fmaf_rn(rr[ni][0], w1b[0][ci], a);
                a = __fmaf_rn(rr[ni][1], w1b[1][ci], a);
                a = __fmaf_rn(rr[ni][2], w1b[2][ci], a);
                a = fmaxf(a + bb[ci], 0.0f);
                (&hv.x)[ci] = (n < nvalid) ? a : 0.0f;
            }
            *(float4*)&u0[h].gs[n][c0] = hv;       // in-place h1
        }
    }
    __syncthreads();

    // ======== phase 3: h2 = relu(h1 @ W2 + b2); masked max over n ==========
    {
        const float (*h1)[68] = u0[h].gs;
        const int c4 = (th & 15) * 4;
        const int nb = (th >> 4) * 4;
        float acc[4][8];
        #pragma unroll
        for (int ni = 0; ni < 4; ++ni)
            #pragma unroll
            for (int k = 0; k < 8; ++k) acc[ni][k] = 0.0f;

        #pragma unroll 4
        for (int ccb = 0; ccb < 16; ++ccb) {
            float4 av[4];
            #pragma unroll
            for (int ni = 0; ni < 4; ++ni)
                av[ni] = *(const float4*)&h1[nb + ni][ccb * 4];
            #pragma unroll
            for (int ci = 0; ci < 4; ++ci) {       // cc = 4*ccb + ci, ascending
                const int cc = ccb * 4 + ci;
                const float4 w0 = *(const float4*)&W2[cc * 128 + c4];
                const float4 w1 = *(const float4*)&W2[cc * 128 + c4 + 64];
                const float wv[8] = {w0.x, w0.y, w0.z, w0.w, w1.x, w1.y, w1.z, w1.w};
                #pragma unroll
                for (int k = 0; k < 8; ++k) {
                    acc[0][k] = __fmaf_rn((&av[0].x)[ci], wv[k], acc[0][k]);
                    acc[1][k] = __fmaf_rn((&av[1].x)[ci], wv[k], acc[1][k]);
                    acc[2][k] = __fmaf_rn((&av[2].x)[ci], wv[k], acc[2][k]);
                    acc[3][k] = __fmaf_rn((&av[3].x)[ci], wv[k], acc[3][k]);
                }
            }
        }
        float m8[8];
        #pragma unroll
        for (int k = 0; k < 8; ++k) {
            const int ch = (k < 4) ? (c4 + k) : (64 + c4 + k - 4);
            const float bb = b2[ch];
            float mm = 0.0f;  // relu floor; valid set nonempty (self)
            #pragma unroll
            for (int ni = 0; ni < 4; ++ni)
                if (nb + ni < nvalid) mm = fmaxf(mm, acc[ni][k] + bb);
            m8[k] = mm;
        }
        #pragma unroll
        for (int k = 0; k < 8; ++k) {              // exact max-reduce over n-groups
            float v = m8[k];
            v = fmaxf(v, __shfl_down(v, 32));
            v = fmaxf(v, __shfl_down(v, 16));
            m8[k] = v;
        }
        if ((th & 63) < 16) {
            #pragma unroll
            for (int k = 0; k < 4; ++k) pmw[h][w][c4 + k]          = m8[k];
            #pragma unroll
            for (int k = 4; k < 8; ++k) pmw[h][w][64 + c4 + k - 4] = m8[k];
        }
    }
    __syncthreads();

    if (th < 128)   // fold 4-wave partial maxes into pmw[h][0] (agg in place)
        pmw[h][0][th] = fmaxf(fmaxf(pmw[h][0][th], pmw[h][1][th]),
                              fmaxf(pmw[h][2][th], pmw[h][3][th]));
    __syncthreads();

    // ======== phase 4: out[i][th] = relu(agg . Wg[:,th] + bg[th]) ==========
    {
        float acc = 0.0f;
        #pragma unroll 8
        for (int k = 0; k < 128; ++k)
            acc = __fmaf_rn(pmw[h][0][k], Wg[k * 256 + th], acc);
        out[i * 256 + th] = fmaxf(acc + bg[th], 0.0f);
    }
}

// ---------------------------------------------------------------------------
extern "C" void kernel_launch(void* const* d_in, const int* in_sizes, int n_in,
                              void* d_out, int out_size, void* d_ws, size_t ws_size,
                              hipStream_t stream) {
    const float* x   = (const float*)d_in[0];
    const float* pos = (const float*)d_in[1];
    // d_in[2] = batch (all zeros) — unused
    const float* W1 = (const float*)d_in[3];
    const float* b1 = (const float*)d_in[4];
    const float* W2 = (const float*)d_in[5];
    const float* b2 = (const float*)d_in[6];
    const float* Wg = (const float*)d_in[7];
    const float* bg = (const float*)d_in[8];
    float* out = (float*)d_out;

    float* g = (float*)d_ws;   // 8192*64 floats = 2 MB, fully written by k_g

    k_g<<<N_PTS / 32, 256, 0, stream>>>(x, W1, g);
    fused_all<<<N_PTS / 2, 512, 0, stream>>>(g, pos, W1, b1, W2, b2, Wg, bg, out);
}

// Round 7
// 424.599 us; speedup vs baseline: 1.0513x; 1.0513x over previous
//
#include <hip/hip_runtime.h>

#define N_PTS 8192
#define R2F 0.015625f   // R*R, exactly representable

// ---------------- g = x @ W1a (NO bias; R16 chain verbatim, 32-row tiles) ---
__global__ __launch_bounds__(256) void k_g(const float* __restrict__ x,
                                           const float* __restrict__ W1,
                                           float* __restrict__ g) {
    __shared__ float xs[32][68];
    __shared__ float ws_[64][64];
    const int t = threadIdx.x;
    const int r0 = blockIdx.x * 32;
    for (int v = t; v < 1024; v += 256)
        ((float4*)&ws_[0][0])[v] = ((const float4*)W1)[v];   // W1 rows 0..63
    for (int v = t; v < 512; v += 256) {
        const int n = v >> 4, c4 = (v & 15) * 4;
        *(float4*)&xs[n][c4] = *(const float4*)&x[(r0 + n) * 64 + c4];
    }
    __syncthreads();
    const int c0 = (t & 15) * 4, n0 = (t >> 4) * 2;
    float acc[2][4];
    #pragma unroll
    for (int ni = 0; ni < 2; ++ni)
        #pragma unroll
        for (int ci = 0; ci < 4; ++ci) acc[ni][ci] = 0.0f;
    #pragma unroll
    for (int kb4 = 0; kb4 < 16; ++kb4) {
        float4 av[2], wv[4];
        #pragma unroll
        for (int ni = 0; ni < 2; ++ni)
            av[ni] = *(const float4*)&xs[n0 + ni][kb4 * 4];
        #pragma unroll
        for (int ki = 0; ki < 4; ++ki)
            wv[ki] = *(const float4*)&ws_[kb4 * 4 + ki][c0];
        #pragma unroll
        for (int ki = 0; ki < 4; ++ki) {           // k = 4*kb4 + ki, ascending
            #pragma unroll
            for (int ni = 0; ni < 2; ++ni) {
                const float a = (&av[ni].x)[ki];
                acc[ni][0] = __fmaf_rn(a, wv[ki].x, acc[ni][0]);
                acc[ni][1] = __fmaf_rn(a, wv[ki].y, acc[ni][1]);
                acc[ni][2] = __fmaf_rn(a, wv[ki].z, acc[ni][2]);
                acc[ni][3] = __fmaf_rn(a, wv[ki].w, acc[ni][3]);
            }
        }
    }
    #pragma unroll
    for (int ni = 0; ni < 2; ++ni)
        *(float4*)&g[(r0 + n0 + ni) * 64 + c0] =
            make_float4(acc[ni][0], acc[ni][1], acc[ni][2], acc[ni][3]);
}

// Bit-exact d2 key: shared by phase 1 and the rare rescan path. Identical
// intrinsic DAG (__fmul/__fadd/__fmaf/__fsub _rn) -> identical bits at both
// call sites (IEEE determinism; no reassociation possible on intrinsics).
__device__ __forceinline__ unsigned d2key(const float* __restrict__ pos, int j,
                                          float xi, float yi, float zi,
                                          float sqi) {
    const float xj = pos[j * 3 + 0], yj = pos[j * 3 + 1], zj = pos[j * 3 + 2];
    const float sqj = __fadd_rn(__fadd_rn(__fmul_rn(xj, xj), __fmul_rn(yj, yj)),
                                __fmul_rn(zj, zj));
    const float dot = __fmaf_rn(zi, zj, __fmaf_rn(yi, yj, __fmul_rn(xi, xj)));
    const float d2  = __fsub_rn(__fadd_rn(sqi, sqj), __fmul_rn(2.0f, dot));
    unsigned b = __float_as_uint(d2);
    return (b & 0x80000000u) ? ~b : (b | 0x80000000u);  // monotone total order
}

// ---------------- main fused kernel ----------------------------------------
// VGPR-slimmed variant of the 420-us baseline. Measured dose-response
// (R2/R4/R6: VGPR 56->13.7 waves/CU, 52->13.3, 32->25.9) fits an effective
// VGPR pool of ~256/lane/SIMD: waves/SIMD = floor(256/VGPR). Baseline peaked
// at 56 (kb[32] in phase 1; acc[4][8]+av[4] in phase 3) -> 4 waves/SIMD.
// This version: top-4 min tracking (8 regs, rescan-recompute at level>=4)
// and channel-split phase 3 (acc[4][4] + 4-row W2 tile) -> target <=48 regs
// -> 5-6 waves/SIMD. All FMA chains remain in the proven ascending order.
union U0 {
    struct { unsigned mb[4][64]; unsigned mj[4][64]; } s;   // 2 KB
    float gs[64][68];                                       // 17408 B
};

__global__ __launch_bounds__(256, 10) void fused_all(const float* __restrict__ g,
                                                     const float* __restrict__ pos,
                                                     const float* __restrict__ W1,
                                                     const float* __restrict__ b1,
                                                     const float* __restrict__ W2,
                                                     const float* __restrict__ b2,
                                                     const float* __restrict__ Wg,
                                                     const float* __restrict__ bg,
                                                     float* __restrict__ out) {
    __shared__ U0    u0;             // 17408 B (total ~20.5 KB)
    __shared__ float pmw[4][128];    // 2 KB
    __shared__ float aggS[128];
    __shared__ unsigned selb[64];
    __shared__ int   selj[64];
    __shared__ int   nvalidS;

    const int t    = threadIdx.x;
    const int lane = t & 63;
    const int w    = t >> 6;         // wave id; owns quarter j in [2048w, 2048w+2048)
    const int qb   = w << 11;
    const int i    = blockIdx.x;

    const float xi = pos[i * 3 + 0], yi = pos[i * 3 + 1], zi = pos[i * 3 + 2];
    const float sqi = __fadd_rn(__fadd_rn(__fmul_rn(xi, xi), __fmul_rn(yi, yi)),
                                __fmul_rn(zi, zi));

    // ---- phase 1: d2 keys; track per-lane FOUR smallest (b, j) ----
    // Strict '<' + ascending j => on b-tie the incumbent (smaller j) wins,
    // so (m1..m4) are the lane's 4 smallest keys in (b, j) lexicographic
    // order — identical selection semantics to the proven kb[]-based scan.
    unsigned m1b = 0xFFFFFFFFu, m2b = 0xFFFFFFFFu,
             m3b = 0xFFFFFFFFu, m4b = 0xFFFFFFFFu;
    int      m1j = 0x7FFFFFFF,  m2j = 0x7FFFFFFF,
             m3j = 0x7FFFFFFF,  m4j = 0x7FFFFFFF;
    #pragma unroll
    for (int k = 0; k < 32; ++k) {
        const int j = qb + lane + (k << 6);
        const unsigned b = d2key(pos, j, xi, yi, zi, sqi);
        if (b < m1b) {
            m4b = m3b; m4j = m3j; m3b = m2b; m3j = m2j;
            m2b = m1b; m2j = m1j; m1b = b;   m1j = j;
        } else if (b < m2b) {
            m4b = m3b; m4j = m3j; m3b = m2b; m3j = m2j;
            m2b = b;   m2j = j;
        } else if (b < m3b) {
            m4b = m3b; m4j = m3j; m3b = b;   m3j = j;
        } else if (b < m4b) {
            m4b = b;   m4j = j;
        }
    }

    // unique ascending pads: no rank collisions in the merge (the R9 bug)
    u0.s.mb[w][lane] = 0xFFFFFFFFu;
    u0.s.mj[w][lane] = 0xFFFFFF00u | (unsigned)((w << 6) | lane);

    // ---- pops with early exit; lazy lane-min: m1->m2->m3->m4->rescan ----
    // A lane's owned pops ascend, so after its r-th owned pop the lane-min
    // over unremoved keys is m(r+1) for r<=3; at level>=4 (rare, ~1/wave)
    // recompute keys bit-exactly from pos and scan the removed mask.
    unsigned removed = 0u;
    int      level = 0;
    unsigned lb = m1b;
    int      lj = m1j;
    for (int s = 0; s < 64; ++s) {
        unsigned rb = lb;
        int      rj = lj;
        #pragma unroll
        for (int off = 32; off > 0; off >>= 1) {
            const unsigned ob = (unsigned)__shfl_down((int)rb, off);
            const int      oj = __shfl_down(rj, off);
            if (ob < rb || (ob == rb && oj < rj)) { rb = ob; rj = oj; }
        }
        const unsigned wb = (unsigned)__shfl((int)rb, 0);
        const int      wj = __shfl(rj, 0);
        const unsigned db = (wb & 0x80000000u) ? (wb ^ 0x80000000u) : ~wb;
        if (!(__uint_as_float(db) <= R2F)) break;   // wave-uniform; pops ascend
        if (lane == 0) { u0.s.mb[w][s] = wb; u0.s.mj[w][s] = (unsigned)wj; }
        if (lb == wb && lj == wj) {                 // unique owner lane
            removed |= 1u << ((wj - qb - lane) >> 6);
            ++level;
            if      (level == 1) { lb = m2b; lj = m2j; }
            else if (level == 2) { lb = m3b; lj = m3j; }
            else if (level == 3) { lb = m4b; lj = m4j; }
            else {                                  // rare: recompute rescan
                lb = 0xFFFFFFFFu; lj = 0x7FFFFFFF;
                #pragma unroll 4
                for (int k = 0; k < 32; ++k) {
                    if (!(removed & (1u << k))) {
                        const int jr = qb + lane + (k << 6);
                        const unsigned b = d2key(pos, jr, xi, yi, zi, sqi);
                        if (b < lb) { lb = b; lj = jr; }  // j asc: ties keep incumbent
                    }
                }
            }
        }
    }
    __syncthreads();

    {   // merge: exact global top-64 by (b, j) via parallel rank (bijective)
        const int p = lane;
        const unsigned be = u0.s.mb[w][p];
        const unsigned je = u0.s.mj[w][p];
        int rank = p;
        #pragma unroll
        for (int d = 1; d < 4; ++d) {
            const int wp = (w + d) & 3;
            int lo = 0;
            #pragma unroll
            for (int st = 32; st > 0; st >>= 1) {
                const int idx = lo + st - 1;
                const unsigned ob = u0.s.mb[wp][idx];
                const unsigned oj = u0.s.mj[wp][idx];
                if (ob < be || (ob == be && oj < je)) lo += st;
            }
            {
                const unsigned ob = u0.s.mb[wp][lo];
                const unsigned oj = u0.s.mj[wp][lo];
                if (ob < be || (ob == be && oj < je)) lo += 1;
            }
            rank += lo;
        }
        if (rank < 64) { selb[rank] = be; selj[rank] = (int)(je & 8191u); }
    }
    __syncthreads();

    // ======== gather g rows (overwrites mb/mj), nvalid ballot ==============
    for (int v = t; v < 1024; v += 256) {
        const int n = v >> 4, c4 = (v & 15) * 4;   // rows >= nvalid never used
        *(float4*)&u0.gs[n][c4] = *(const float4*)&g[selj[n] * 64 + c4];
    }
    {
        bool ok = false;
        if (t < 64) {
            const unsigned b = selb[t];
            const unsigned db = (b & 0x80000000u) ? (b ^ 0x80000000u) : ~b;
            ok = (__uint_as_float(db) <= R2F);     // pads decode NaN -> false
        }
        const unsigned long long vm = __ballot(ok);
        if (t == 0) nvalidS = __popcll(vm);        // asc d2 -> popcount == prefix
    }
    __syncthreads();
    const int nvalid = nvalidS;

    // ======== phase 2: h1 = relu(g + rel @ W1b + b1), IN PLACE over gs ======
    // Each (n, c0..c0+3) slot is read and written by its owning thread only.
    {
        const int c0 = (t & 15) * 4, n0 = (t >> 4) * 4;
        float rr[4][3];
        #pragma unroll
        for (int ni = 0; ni < 4; ++ni) {
            const int j = selj[n0 + ni];
            rr[ni][0] = pos[j * 3 + 0] - xi;
            rr[ni][1] = pos[j * 3 + 1] - yi;
            rr[ni][2] = pos[j * 3 + 2] - zi;
        }
        float w1b[3][4], bb[4];
        #pragma unroll
        for (int ci = 0; ci < 4; ++ci) {
            w1b[0][ci] = W1[4096 + c0 + ci];
            w1b[1][ci] = W1[4160 + c0 + ci];
            w1b[2][ci] = W1[4224 + c0 + ci];
            bb[ci]     = b1[c0 + ci];
        }
        #pragma unroll
        for (int ni = 0; ni < 4; ++ni) {
            const int n = n0 + ni;
            const float4 gv = *(const float4*)&u0.gs[n][c0];
            float4 hv;
            #pragma unroll
            for (int ci = 0; ci < 4; ++ci) {
                float a = (&gv.x)[ci];             // == full ascending-k sum
                a = __fmaf_rn(rr[ni][0], w1b[0][ci], a);
                a = __fmaf_rn(rr[ni][1], w1b[1][ci], a);
                a = __fmaf_rn(rr[ni][2], w1b[2][ci], a);
                a = fmaxf(a + bb[ci], 0.0f);
                (&hv.x)[ci] = (n < nvalid) ? a : 0.0f;
            }
            *(float4*)&u0.gs[n][c0] = hv;          // in-place h1
        }
    }
    __syncthreads();

    // ======== phase 3: h2 = relu(h1 @ W2 + b2); masked max over n ==========
    // Channel-split: two passes of 4 channels each (acc[4][4] + 4-row W2
    // tile) instead of one 8-channel pass. Per-output FMA chain still runs
    // cc = 0..127 strictly ascending -> bit-identical results; halves the
    // phase-3 register peak (acc 32->16, w 8->16 but av 16->4).
    {
        const float (*h1)[68] = u0.gs;
        const int c4 = (t & 15) * 4;
        const int nb = (t >> 4) * 4;
        #pragma unroll
        for (int half = 0; half < 2; ++half) {
            const int ch0 = half * 64 + c4;
            float acc[4][4];
            #pragma unroll
            for (int ni = 0; ni < 4; ++ni)
                #pragma unroll
                for (int k = 0; k < 4; ++k) acc[ni][k] = 0.0f;

            #pragma unroll 4
            for (int ccb = 0; ccb < 16; ++ccb) {
                float4 wt[4];
                #pragma unroll
                for (int ci = 0; ci < 4; ++ci)
                    wt[ci] = *(const float4*)&W2[(ccb * 4 + ci) * 128 + ch0];
                #pragma unroll
                for (int ni = 0; ni < 4; ++ni) {
                    const float4 av = *(const float4*)&h1[nb + ni][ccb * 4];
                    #pragma unroll
                    for (int ci = 0; ci < 4; ++ci) {   // cc ascending per output
                        const float a = (&av.x)[ci];
                        acc[ni][0] = __fmaf_rn(a, wt[ci].x, acc[ni][0]);
                        acc[ni][1] = __fmaf_rn(a, wt[ci].y, acc[ni][1]);
                        acc[ni][2] = __fmaf_rn(a, wt[ci].z, acc[ni][2]);
                        acc[ni][3] = __fmaf_rn(a, wt[ci].w, acc[ni][3]);
                    }
                }
            }
            float m4v[4];
            #pragma unroll
            for (int k = 0; k < 4; ++k) {
                const float bb = b2[ch0 + k];
                float mm = 0.0f;  // relu floor; valid set nonempty (self)
                #pragma unroll
                for (int ni = 0; ni < 4; ++ni)
                    if (nb + ni < nvalid) mm = fmaxf(mm, acc[ni][k] + bb);
                m4v[k] = mm;
            }
            #pragma unroll
            for (int k = 0; k < 4; ++k) {          // exact max-reduce over n-groups
                float v = m4v[k];
                v = fmaxf(v, __shfl_down(v, 32));
                v = fmaxf(v, __shfl_down(v, 16));
                m4v[k] = v;
            }
            if ((t & 63) < 16) {
                #pragma unroll
                for (int k = 0; k < 4; ++k) pmw[w][ch0 + k] = m4v[k];
            }
        }
    }
    __syncthreads();

    if (t < 128)
        aggS[t] = fmaxf(fmaxf(pmw[0][t], pmw[1][t]),
                        fmaxf(pmw[2][t], pmw[3][t]));
    __syncthreads();

    // ======== phase 4: out[i][t] = relu(aggS . Wg[:,t] + bg[t]) ============
    {
        float acc = 0.0f;
        #pragma unroll 8
        for (int k = 0; k < 128; ++k)
            acc = __fmaf_rn(aggS[k], Wg[k * 256 + t], acc);
        out[i * 256 + t] = fmaxf(acc + bg[t], 0.0f);
    }
}

// ---------------------------------------------------------------------------
extern "C" void kernel_launch(void* const* d_in, const int* in_sizes, int n_in,
                              void* d_out, int out_size, void* d_ws, size_t ws_size,
                              hipStream_t stream) {
    const float* x   = (const float*)d_in[0];
    const float* pos = (const float*)d_in[1];
    // d_in[2] = batch (all zeros) — unused
    const float* W1 = (const float*)d_in[3];
    const float* b1 = (const float*)d_in[4];
    const float* W2 = (const float*)d_in[5];
    const float* b2 = (const float*)d_in[6];
    const float* Wg = (const float*)d_in[7];
    const float* bg = (const float*)d_in[8];
    float* out = (float*)d_out;

    float* g = (float*)d_ws;   // 8192*64 floats = 2 MB, fully written by k_g

    k_g<<<N_PTS / 32, 256, 0, stream>>>(x, W1, g);
    fused_all<<<N_PTS, 256, 0, stream>>>(g, pos, W1, b1, W2, b2, Wg, bg, out);
}

// Round 10
// 388.350 us; speedup vs baseline: 1.1495x; 1.0933x over previous
//
#include <hip/hip_runtime.h>

#define N_PTS 8192
#define R2F 0.015625f   // R*R, exactly representable

// ---------------- g = x @ W1a (NO bias; R16 chain verbatim, 32-row tiles) ---
__global__ __launch_bounds__(256) void k_g(const float* __restrict__ x,
                                           const float* __restrict__ W1,
                                           float* __restrict__ g) {
    __shared__ float xs[32][68];
    __shared__ float ws_[64][64];
    const int t = threadIdx.x;
    const int r0 = blockIdx.x * 32;
    for (int v = t; v < 1024; v += 256)
        ((float4*)&ws_[0][0])[v] = ((const float4*)W1)[v];   // W1 rows 0..63
    for (int v = t; v < 512; v += 256) {
        const int n = v >> 4, c4 = (v & 15) * 4;
        *(float4*)&xs[n][c4] = *(const float4*)&x[(r0 + n) * 64 + c4];
    }
    __syncthreads();
    const int c0 = (t & 15) * 4, n0 = (t >> 4) * 2;
    float acc[2][4];
    #pragma unroll
    for (int ni = 0; ni < 2; ++ni)
        #pragma unroll
        for (int ci = 0; ci < 4; ++ci) acc[ni][ci] = 0.0f;
    #pragma unroll
    for (int kb4 = 0; kb4 < 16; ++kb4) {
        float4 av[2], wv[4];
        #pragma unroll
        for (int ni = 0; ni < 2; ++ni)
            av[ni] = *(const float4*)&xs[n0 + ni][kb4 * 4];
        #pragma unroll
        for (int ki = 0; ki < 4; ++ki)
            wv[ki] = *(const float4*)&ws_[kb4 * 4 + ki][c0];
        #pragma unroll
        for (int ki = 0; ki < 4; ++ki) {           // k = 4*kb4 + ki, ascending
            #pragma unroll
            for (int ni = 0; ni < 2; ++ni) {
                const float a = (&av[ni].x)[ki];
                acc[ni][0] = __fmaf_rn(a, wv[ki].x, acc[ni][0]);
                acc[ni][1] = __fmaf_rn(a, wv[ki].y, acc[ni][1]);
                acc[ni][2] = __fmaf_rn(a, wv[ki].z, acc[ni][2]);
                acc[ni][3] = __fmaf_rn(a, wv[ki].w, acc[ni][3]);
            }
        }
    }
    #pragma unroll
    for (int ni = 0; ni < 2; ++ni)
        *(float4*)&g[(r0 + n0 + ni) * 64 + c0] =
            make_float4(acc[ni][0], acc[ni][1], acc[ni][2], acc[ni][3]);
}

// Bit-exact d2 key: shared by phase 1 and the rare rescan path. Identical
// intrinsic DAG (__fmul/__fadd/__fmaf/__fsub _rn) -> identical bits at both
// call sites (IEEE determinism; no reassociation possible on intrinsics).
__device__ __forceinline__ unsigned d2key(const float* __restrict__ pos, int j,
                                          float xi, float yi, float zi,
                                          float sqi) {
    const float xj = pos[j * 3 + 0], yj = pos[j * 3 + 1], zj = pos[j * 3 + 2];
    const float sqj = __fadd_rn(__fadd_rn(__fmul_rn(xj, xj), __fmul_rn(yj, yj)),
                                __fmul_rn(zj, zj));
    const float dot = __fmaf_rn(zi, zj, __fmaf_rn(yi, yj, __fmul_rn(xi, xj)));
    const float d2  = __fsub_rn(__fadd_rn(sqi, sqj), __fmul_rn(2.0f, dot));
    unsigned b = __float_as_uint(d2);
    return (b & 0x80000000u) ? ~b : (b | 0x80000000u);  // monotone total order
}

// ---------------- main fused kernel ----------------------------------------
// Occupancy model (4 measured points, R2/R4/R6/R7): effective VGPR pool is
// ~256/lane/SIMD -> waves/SIMD = floor(256/VGPR). 52 and 56 both give 4
// waves/SIMD (measured 13.3-13.7 waves/CU); 32 gives 8 (measured 25.9).
// Target: cross the 48-reg boundary -> 5 waves/SIMD. __launch_bounds__(256,5)
// caps at 51 under BOTH plausible arg-2 semantics; phase 3 is slimmed to a
// ~40-reg peak (wt[2] W2 tile + float2 h1 reads) so the cap doesn't spill.
union U0 {
    struct { unsigned mb[4][64]; unsigned mj[4][64]; } s;   // 2 KB
    float gs[64][68];                                       // 17408 B
};

__global__ __launch_bounds__(256, 5) void fused_all(const float* __restrict__ g,
                                                    const float* __restrict__ pos,
                                                    const float* __restrict__ W1,
                                                    const float* __restrict__ b1,
                                                    const float* __restrict__ W2,
                                                    const float* __restrict__ b2,
                                                    const float* __restrict__ Wg,
                                                    const float* __restrict__ bg,
                                                    float* __restrict__ out) {
    __shared__ U0    u0;             // 17408 B (total ~20.5 KB)
    __shared__ float pmw[4][128];    // 2 KB
    __shared__ float aggS[128];
    __shared__ unsigned selb[64];
    __shared__ int   selj[64];
    __shared__ int   nvalidS;

    const int t    = threadIdx.x;
    const int lane = t & 63;
    const int w    = t >> 6;         // wave id; owns quarter j in [2048w, 2048w+2048)
    const int qb   = w << 11;
    const int i    = blockIdx.x;

    const float xi = pos[i * 3 + 0], yi = pos[i * 3 + 1], zi = pos[i * 3 + 2];
    const float sqi = __fadd_rn(__fadd_rn(__fmul_rn(xi, xi), __fmul_rn(yi, yi)),
                                __fmul_rn(zi, zi));

    // ---- phase 1: d2 keys; track per-lane FOUR smallest (b, j) ----
    // Strict '<' + ascending j => on b-tie the incumbent (smaller j) wins,
    // so (m1..m4) are the lane's 4 smallest keys in (b, j) lexicographic
    // order — identical selection semantics to the proven kb[]-based scan.
    unsigned m1b = 0xFFFFFFFFu, m2b = 0xFFFFFFFFu,
             m3b = 0xFFFFFFFFu, m4b = 0xFFFFFFFFu;
    int      m1j = 0x7FFFFFFF,  m2j = 0x7FFFFFFF,
             m3j = 0x7FFFFFFF,  m4j = 0x7FFFFFFF;
    #pragma unroll
    for (int k = 0; k < 32; ++k) {
        const int j = qb + lane + (k << 6);
        const unsigned b = d2key(pos, j, xi, yi, zi, sqi);
        if (b < m1b) {
            m4b = m3b; m4j = m3j; m3b = m2b; m3j = m2j;
            m2b = m1b; m2j = m1j; m1b = b;   m1j = j;
        } else if (b < m2b) {
            m4b = m3b; m4j = m3j; m3b = m2b; m3j = m2j;
            m2b = b;   m2j = j;
        } else if (b < m3b) {
            m4b = m3b; m4j = m3j; m3b = b;   m3j = j;
        } else if (b < m4b) {
            m4b = b;   m4j = j;
        }
    }

    // unique ascending pads: no rank collisions in the merge (the R9 bug)
    u0.s.mb[w][lane] = 0xFFFFFFFFu;
    u0.s.mj[w][lane] = 0xFFFFFF00u | (unsigned)((w << 6) | lane);

    // ---- pops with early exit; lazy lane-min: m1->m2->m3->m4->rescan ----
    // A lane's owned pops ascend, so after its r-th owned pop the lane-min
    // over unremoved keys is m(r+1) for r<=3; at level>=4 (rare, ~1/wave)
    // recompute keys bit-exactly from pos and scan the removed mask.
    unsigned removed = 0u;
    int      level = 0;
    unsigned lb = m1b;
    int      lj = m1j;
    for (int s = 0; s < 64; ++s) {
        unsigned rb = lb;
        int      rj = lj;
        #pragma unroll
        for (int off = 32; off > 0; off >>= 1) {
            const unsigned ob = (unsigned)__shfl_down((int)rb, off);
            const int      oj = __shfl_down(rj, off);
            if (ob < rb || (ob == rb && oj < rj)) { rb = ob; rj = oj; }
        }
        const unsigned wb = (unsigned)__shfl((int)rb, 0);
        const int      wj = __shfl(rj, 0);
        const unsigned db = (wb & 0x80000000u) ? (wb ^ 0x80000000u) : ~wb;
        if (!(__uint_as_float(db) <= R2F)) break;   // wave-uniform; pops ascend
        if (lane == 0) { u0.s.mb[w][s] = wb; u0.s.mj[w][s] = (unsigned)wj; }
        if (lb == wb && lj == wj) {                 // unique owner lane
            removed |= 1u << ((wj - qb - lane) >> 6);
            ++level;
            if      (level == 1) { lb = m2b; lj = m2j; }
            else if (level == 2) { lb = m3b; lj = m3j; }
            else if (level == 3) { lb = m4b; lj = m4j; }
            else {                                  // rare: recompute rescan
                lb = 0xFFFFFFFFu; lj = 0x7FFFFFFF;
                #pragma unroll 4
                for (int k = 0; k < 32; ++k) {
                    if (!(removed & (1u << k))) {
                        const int jr = qb + lane + (k << 6);
                        const unsigned b = d2key(pos, jr, xi, yi, zi, sqi);
                        if (b < lb) { lb = b; lj = jr; }  // j asc: ties keep incumbent
                    }
                }
            }
        }
    }
    __syncthreads();

    {   // merge: exact global top-64 by (b, j) via parallel rank (bijective)
        const int p = lane;
        const unsigned be = u0.s.mb[w][p];
        const unsigned je = u0.s.mj[w][p];
        int rank = p;
        #pragma unroll
        for (int d = 1; d < 4; ++d) {
            const int wp = (w + d) & 3;
            int lo = 0;
            #pragma unroll
            for (int st = 32; st > 0; st >>= 1) {
                const int idx = lo + st - 1;
                const unsigned ob = u0.s.mb[wp][idx];
                const unsigned oj = u0.s.mj[wp][idx];
                if (ob < be || (ob == be && oj < je)) lo += st;
            }
            {
                const unsigned ob = u0.s.mb[wp][lo];
                const unsigned oj = u0.s.mj[wp][lo];
                if (ob < be || (ob == be && oj < je)) lo += 1;
            }
            rank += lo;
        }
        if (rank < 64) { selb[rank] = be; selj[rank] = (int)(je & 8191u); }
    }
    __syncthreads();

    // ======== gather g rows (overwrites mb/mj), nvalid ballot ==============
    for (int v = t; v < 1024; v += 256) {
        const int n = v >> 4, c4 = (v & 15) * 4;   // rows >= nvalid never used
        *(float4*)&u0.gs[n][c4] = *(const float4*)&g[selj[n] * 64 + c4];
    }
    {
        bool ok = false;
        if (t < 64) {
            const unsigned b = selb[t];
            const unsigned db = (b & 0x80000000u) ? (b ^ 0x80000000u) : ~b;
            ok = (__uint_as_float(db) <= R2F);     // pads decode NaN -> false
        }
        const unsigned long long vm = __ballot(ok);
        if (t == 0) nvalidS = __popcll(vm);        // asc d2 -> popcount == prefix
    }
    __syncthreads();
    const int nvalid = nvalidS;

    // ======== phase 2: h1 = relu(g + rel @ W1b + b1), IN PLACE over gs ======
    // Each (n, c0..c0+3) slot is read and written by its owning thread only.
    {
        const int c0 = (t & 15) * 4, n0 = (t >> 4) * 4;
        float rr[4][3];
        #pragma unroll
        for (int ni = 0; ni < 4; ++ni) {
            const int j = selj[n0 + ni];
            rr[ni][0] = pos[j * 3 + 0] - xi;
            rr[ni][1] = pos[j * 3 + 1] - yi;
            rr[ni][2] = pos[j * 3 + 2] - zi;
        }
        float w1b[3][4], bb[4];
        #pragma unroll
        for (int ci = 0; ci < 4; ++ci) {
            w1b[0][ci] = W1[4096 + c0 + ci];
            w1b[1][ci] = W1[4160 + c0 + ci];
            w1b[2][ci] = W1[4224 + c0 + ci];
            bb[ci]     = b1[c0 + ci];
        }
        #pragma unroll
        for (int ni = 0; ni < 4; ++ni) {
            const int n = n0 + ni;
            const float4 gv = *(const float4*)&u0.gs[n][c0];
            float4 hv;
            #pragma unroll
            for (int ci = 0; ci < 4; ++ci) {
                float a = (&gv.x)[ci];             // == full ascending-k sum
                a = __fmaf_rn(rr[ni][0], w1b[0][ci], a);
                a = __fmaf_rn(rr[ni][1], w1b[1][ci], a);
                a = __fmaf_rn(rr[ni][2], w1b[2][ci], a);
                a = fmaxf(a + bb[ci], 0.0f);
                (&hv.x)[ci] = (n < nvalid) ? a : 0.0f;
            }
            *(float4*)&u0.gs[n][c0] = hv;          // in-place h1
        }
    }
    __syncthreads();

    // ======== phase 3: h2 = relu(h1 @ W2 + b2); masked max over n ==========
    // Channel-split (two 4-ch halves) with a 2-row W2 tile and float2 h1
    // reads: register peak ~ acc16 + wt8 + av2 + addr. Per-output FMA chain
    // still runs cc = 0..63 strictly ascending -> bit-identical results.
    {
        const float (*h1)[68] = u0.gs;
        const int c4 = (t & 15) * 4;
        const int nb = (t >> 4) * 4;
        #pragma unroll
        for (int half = 0; half < 2; ++half) {
            const int ch0 = half * 64 + c4;
            float acc[4][4];
            #pragma unroll
            for (int ni = 0; ni < 4; ++ni)
                #pragma unroll
                for (int k = 0; k < 4; ++k) acc[ni][k] = 0.0f;

            #pragma unroll 2
            for (int ccb = 0; ccb < 16; ++ccb) {
                #pragma unroll
                for (int pr = 0; pr < 2; ++pr) {   // cc = ccb*4 + pr*2 + {0,1}
                    const int cc0 = ccb * 4 + pr * 2;
                    const float4 wt0 = *(const float4*)&W2[(cc0 + 0) * 128 + ch0];
                    const float4 wt1 = *(const float4*)&W2[(cc0 + 1) * 128 + ch0];
                    #pragma unroll
                    for (int ni = 0; ni < 4; ++ni) {
                        const float2 av = *(const float2*)&h1[nb + ni][cc0];
                        acc[ni][0] = __fmaf_rn(av.x, wt0.x, acc[ni][0]);
                        acc[ni][1] = __fmaf_rn(av.x, wt0.y, acc[ni][1]);
                        acc[ni][2] = __fmaf_rn(av.x, wt0.z, acc[ni][2]);
                        acc[ni][3] = __fmaf_rn(av.x, wt0.w, acc[ni][3]);
                        acc[ni][0] = __fmaf_rn(av.y, wt1.x, acc[ni][0]);
                        acc[ni][1] = __fmaf_rn(av.y, wt1.y, acc[ni][1]);
                        acc[ni][2] = __fmaf_rn(av.y, wt1.z, acc[ni][2]);
                        acc[ni][3] = __fmaf_rn(av.y, wt1.w, acc[ni][3]);
                    }
                }
            }
            float m4v[4];
            #pragma unroll
            for (int k = 0; k < 4; ++k) {
                const float bb = b2[ch0 + k];
                float mm = 0.0f;  // relu floor; valid set nonempty (self)
                #pragma unroll
                for (int ni = 0; ni < 4; ++ni)
                    if (nb + ni < nvalid) mm = fmaxf(mm, acc[ni][k] + bb);
                m4v[k] = mm;
            }
            #pragma unroll
            for (int k = 0; k < 4; ++k) {          // exact max-reduce over n-groups
                float v = m4v[k];
                v = fmaxf(v, __shfl_down(v, 32));
                v = fmaxf(v, __shfl_down(v, 16));
                m4v[k] = v;
            }
            if ((t & 63) < 16) {
                #pragma unroll
                for (int k = 0; k < 4; ++k) pmw[w][ch0 + k] = m4v[k];
            }
        }
    }
    __syncthreads();

    if (t < 128)
        aggS[t] = fmaxf(fmaxf(pmw[0][t], pmw[1][t]),
                        fmaxf(pmw[2][t], pmw[3][t]));
    __syncthreads();

    // ======== phase 4: out[i][t] = relu(aggS . Wg[:,t] + bg[t]) ============
    {
        float acc = 0.0f;
        #pragma unroll 8
        for (int k = 0; k < 128; ++k)
            acc = __fmaf_rn(aggS[k], Wg[k * 256 + t], acc);
        out[i * 256 + t] = fmaxf(acc + bg[t], 0.0f);
    }
}

// ---------------------------------------------------------------------------
extern "C" void kernel_launch(void* const* d_in, const int* in_sizes, int n_in,
                              void* d_out, int out_size, void* d_ws, size_t ws_size,
                              hipStream_t stream) {
    const float* x   = (const float*)d_in[0];
    const float* pos = (const float*)d_in[1];
    // d_in[2] = batch (all zeros) — unused
    const float* W1 = (const float*)d_in[3];
    const float* b1 = (const float*)d_in[4];
    const float* W2 = (const float*)d_in[5];
    const float* b2 = (const float*)d_in[6];
    const float* Wg = (const float*)d_in[7];
    const float* bg = (const float*)d_in[8];
    float* out = (float*)d_out;

    float* g = (float*)d_ws;   // 8192*64 floats = 2 MB, fully written by k_g

    k_g<<<N_PTS / 32, 256, 0, stream>>>(x, W1, g);
    fused_all<<<N_PTS, 256, 0, stream>>>(g, pos, W1, b1, W2, b2, Wg, bg, out);
}

// Round 11
// 380.494 us; speedup vs baseline: 1.1732x; 1.0206x over previous
//
#include <hip/hip_runtime.h>

#define N_PTS 8192
#define R2F 0.015625f   // R*R, exactly representable

// ---------------- g = x @ W1a (NO bias; R16 chain verbatim, 32-row tiles) ---
__global__ __launch_bounds__(256) void k_g(const float* __restrict__ x,
                                           const float* __restrict__ W1,
                                           float* __restrict__ g) {
    __shared__ float xs[32][68];
    __shared__ float ws_[64][64];
    const int t = threadIdx.x;
    const int r0 = blockIdx.x * 32;
    for (int v = t; v < 1024; v += 256)
        ((float4*)&ws_[0][0])[v] = ((const float4*)W1)[v];   // W1 rows 0..63
    for (int v = t; v < 512; v += 256) {
        const int n = v >> 4, c4 = (v & 15) * 4;
        *(float4*)&xs[n][c4] = *(const float4*)&x[(r0 + n) * 64 + c4];
    }
    __syncthreads();
    const int c0 = (t & 15) * 4, n0 = (t >> 4) * 2;
    float acc[2][4];
    #pragma unroll
    for (int ni = 0; ni < 2; ++ni)
        #pragma unroll
        for (int ci = 0; ci < 4; ++ci) acc[ni][ci] = 0.0f;
    #pragma unroll
    for (int kb4 = 0; kb4 < 16; ++kb4) {
        float4 av[2], wv[4];
        #pragma unroll
        for (int ni = 0; ni < 2; ++ni)
            av[ni] = *(const float4*)&xs[n0 + ni][kb4 * 4];
        #pragma unroll
        for (int ki = 0; ki < 4; ++ki)
            wv[ki] = *(const float4*)&ws_[kb4 * 4 + ki][c0];
        #pragma unroll
        for (int ki = 0; ki < 4; ++ki) {           // k = 4*kb4 + ki, ascending
            #pragma unroll
            for (int ni = 0; ni < 2; ++ni) {
                const float a = (&av[ni].x)[ki];
                acc[ni][0] = __fmaf_rn(a, wv[ki].x, acc[ni][0]);
                acc[ni][1] = __fmaf_rn(a, wv[ki].y, acc[ni][1]);
                acc[ni][2] = __fmaf_rn(a, wv[ki].z, acc[ni][2]);
                acc[ni][3] = __fmaf_rn(a, wv[ki].w, acc[ni][3]);
            }
        }
    }
    #pragma unroll
    for (int ni = 0; ni < 2; ++ni)
        *(float4*)&g[(r0 + n0 + ni) * 64 + c0] =
            make_float4(acc[ni][0], acc[ni][1], acc[ni][2], acc[ni][3]);
}

// Bit-exact d2 key: shared by phase 1 and the rare rescan path. Identical
// intrinsic DAG (__fmul/__fadd/__fmaf/__fsub _rn) -> identical bits at both
// call sites (IEEE determinism; no reassociation possible on intrinsics).
__device__ __forceinline__ unsigned d2key(const float* __restrict__ pos, int j,
                                          float xi, float yi, float zi,
                                          float sqi) {
    const float xj = pos[j * 3 + 0], yj = pos[j * 3 + 1], zj = pos[j * 3 + 2];
    const float sqj = __fadd_rn(__fadd_rn(__fmul_rn(xj, xj), __fmul_rn(yj, yj)),
                                __fmul_rn(zj, zj));
    const float dot = __fmaf_rn(zi, zj, __fmaf_rn(yi, yj, __fmul_rn(xi, xj)));
    const float d2  = __fsub_rn(__fadd_rn(sqi, sqj), __fmul_rn(2.0f, dot));
    unsigned b = __float_as_uint(d2);
    return (b & 0x80000000u) ? ~b : (b | 0x80000000u);  // monotone total order
}

// ---------------- k_sel: neighbor selection only ----------------------------
// R10 analysis: selection (phase1+pops+merge) is ~11% of instructions but
// carries the serial 6-level shuffle chains -> est. 35-40% of runtime stall
// at 5 waves/SIMD. Split out, it needs ~28 VGPR -> (256,8) = 8 waves/SIMD,
// hiding the chain 8-deep. Output: 64 packed ushorts (j | valid<<15) per
// point, stored in the FIRST 128 B of the point's own out row (k_mlp block i
// reads then fully overwrites row i -> no cross-block hazard, no ws growth).
// Selection logic is byte-identical to the R10-passed kernel.
__global__ __launch_bounds__(256, 8) void k_sel(const float* __restrict__ pos,
                                                float* __restrict__ out) {
    __shared__ unsigned mb[4][64];
    __shared__ unsigned mj[4][64];

    const int t    = threadIdx.x;
    const int lane = t & 63;
    const int w    = t >> 6;         // wave id; owns quarter j in [2048w, 2048w+2048)
    const int qb   = w << 11;
    const int i    = blockIdx.x;

    const float xi = pos[i * 3 + 0], yi = pos[i * 3 + 1], zi = pos[i * 3 + 2];
    const float sqi = __fadd_rn(__fadd_rn(__fmul_rn(xi, xi), __fmul_rn(yi, yi)),
                                __fmul_rn(zi, zi));

    // ---- phase 1: d2 keys; track per-lane FOUR smallest (b, j) ----
    unsigned m1b = 0xFFFFFFFFu, m2b = 0xFFFFFFFFu,
             m3b = 0xFFFFFFFFu, m4b = 0xFFFFFFFFu;
    int      m1j = 0x7FFFFFFF,  m2j = 0x7FFFFFFF,
             m3j = 0x7FFFFFFF,  m4j = 0x7FFFFFFF;
    #pragma unroll
    for (int k = 0; k < 32; ++k) {
        const int j = qb + lane + (k << 6);
        const unsigned b = d2key(pos, j, xi, yi, zi, sqi);
        if (b < m1b) {
            m4b = m3b; m4j = m3j; m3b = m2b; m3j = m2j;
            m2b = m1b; m2j = m1j; m1b = b;   m1j = j;
        } else if (b < m2b) {
            m4b = m3b; m4j = m3j; m3b = m2b; m3j = m2j;
            m2b = b;   m2j = j;
        } else if (b < m3b) {
            m4b = m3b; m4j = m3j; m3b = b;   m3j = j;
        } else if (b < m4b) {
            m4b = b;   m4j = j;
        }
    }

    // unique ascending pads: no rank collisions in the merge (the R9 bug)
    mb[w][lane] = 0xFFFFFFFFu;
    mj[w][lane] = 0xFFFFFF00u | (unsigned)((w << 6) | lane);

    // ---- pops with early exit; lazy lane-min: m1->m2->m3->m4->rescan ----
    unsigned removed = 0u;
    int      level = 0;
    unsigned lb = m1b;
    int      lj = m1j;
    for (int s = 0; s < 64; ++s) {
        unsigned rb = lb;
        int      rj = lj;
        #pragma unroll
        for (int off = 32; off > 0; off >>= 1) {
            const unsigned ob = (unsigned)__shfl_down((int)rb, off);
            const int      oj = __shfl_down(rj, off);
            if (ob < rb || (ob == rb && oj < rj)) { rb = ob; rj = oj; }
        }
        const unsigned wb = (unsigned)__shfl((int)rb, 0);
        const int      wj = __shfl(rj, 0);
        const unsigned db = (wb & 0x80000000u) ? (wb ^ 0x80000000u) : ~wb;
        if (!(__uint_as_float(db) <= R2F)) break;   // wave-uniform; pops ascend
        if (lane == 0) { mb[w][s] = wb; mj[w][s] = (unsigned)wj; }
        if (lb == wb && lj == wj) {                 // unique owner lane
            removed |= 1u << ((wj - qb - lane) >> 6);
            ++level;
            if      (level == 1) { lb = m2b; lj = m2j; }
            else if (level == 2) { lb = m3b; lj = m3j; }
            else if (level == 3) { lb = m4b; lj = m4j; }
            else {                                  // rare: recompute rescan
                lb = 0xFFFFFFFFu; lj = 0x7FFFFFFF;
                #pragma unroll 4
                for (int k = 0; k < 32; ++k) {
                    if (!(removed & (1u << k))) {
                        const int jr = qb + lane + (k << 6);
                        const unsigned b = d2key(pos, jr, xi, yi, zi, sqi);
                        if (b < lb) { lb = b; lj = jr; }  // j asc: ties keep incumbent
                    }
                }
            }
        }
    }
    __syncthreads();

    {   // merge: exact global top-64 by (b, j) via parallel rank (bijective)
        const int p = lane;
        const unsigned be = mb[w][p];
        const unsigned je = mj[w][p];
        int rank = p;
        #pragma unroll
        for (int d = 1; d < 4; ++d) {
            const int wp = (w + d) & 3;
            int lo = 0;
            #pragma unroll
            for (int st = 32; st > 0; st >>= 1) {
                const int idx = lo + st - 1;
                const unsigned ob = mb[wp][idx];
                const unsigned oj = mj[wp][idx];
                if (ob < be || (ob == be && oj < je)) lo += st;
            }
            {
                const unsigned ob = mb[wp][lo];
                const unsigned oj = mj[wp][lo];
                if (ob < be || (ob == be && oj < je)) lo += 1;
            }
            rank += lo;
        }
        if (rank < 64) {
            const unsigned db = (be & 0x80000000u) ? (be ^ 0x80000000u) : ~be;
            const bool ok = (__uint_as_float(db) <= R2F);  // pads decode NaN -> false
            ((ushort*)(out + (size_t)i * 256))[rank] =
                (ushort)((je & 8191u) | (ok ? 0x8000u : 0u));
        }
    }
}

// ---------------- k_mlp: gather + MLP + max-agg + global_nn -----------------
// Phases 2-4 byte-identical to the R10-passed kernel (48 VGPR, (256,5)).
// Reads its own out row's first 128 B (sel), then fully overwrites the row.
__global__ __launch_bounds__(256, 5) void k_mlp(const float* __restrict__ g,
                                                const float* __restrict__ pos,
                                                const float* __restrict__ W1,
                                                const float* __restrict__ b1,
                                                const float* __restrict__ W2,
                                                const float* __restrict__ b2,
                                                const float* __restrict__ Wg,
                                                const float* __restrict__ bg,
                                                float* __restrict__ out) {
    __shared__ float gs[64][68];     // 17408 B
    __shared__ float pmw[4][128];    // 2 KB
    __shared__ float aggS[128];
    __shared__ int   selj[64];
    __shared__ int   nvalidS;

    const int t = threadIdx.x;
    const int w = t >> 6;
    const int i = blockIdx.x;

    const float xi = pos[i * 3 + 0], yi = pos[i * 3 + 1], zi = pos[i * 3 + 2];

    bool ok = false;
    if (t < 64) {   // wave 0 reads the packed selection from its own out row
        const unsigned sv = ((const ushort*)(out + (size_t)i * 256))[t];
        selj[t] = (int)(sv & 8191u);
        ok = (sv & 0x8000u) != 0u;
    }
    __syncthreads();   // selj visible to all

    // ======== gather g rows; nvalid ballot (wave 0) ========================
    for (int v = t; v < 1024; v += 256) {
        const int n = v >> 4, c4 = (v & 15) * 4;   // rows >= nvalid never used
        *(float4*)&gs[n][c4] = *(const float4*)&g[selj[n] * 64 + c4];
    }
    {
        const unsigned long long vm = __ballot(ok);
        if (t == 0) nvalidS = __popcll(vm);        // asc d2 -> popcount == prefix
    }
    __syncthreads();
    const int nvalid = nvalidS;

    // ======== phase 2: h1 = relu(g + rel @ W1b + b1), IN PLACE over gs ======
    {
        const int c0 = (t & 15) * 4, n0 = (t >> 4) * 4;
        float rr[4][3];
        #pragma unroll
        for (int ni = 0; ni < 4; ++ni) {
            const int j = selj[n0 + ni];
            rr[ni][0] = pos[j * 3 + 0] - xi;
            rr[ni][1] = pos[j * 3 + 1] - yi;
            rr[ni][2] = pos[j * 3 + 2] - zi;
        }
        float w1b[3][4], bb[4];
        #pragma unroll
        for (int ci = 0; ci < 4; ++ci) {
            w1b[0][ci] = W1[4096 + c0 + ci];
            w1b[1][ci] = W1[4160 + c0 + ci];
            w1b[2][ci] = W1[4224 + c0 + ci];
            bb[ci]     = b1[c0 + ci];
        }
        #pragma unroll
        for (int ni = 0; ni < 4; ++ni) {
            const int n = n0 + ni;
            const float4 gv = *(const float4*)&gs[n][c0];
            float4 hv;
            #pragma unroll
            for (int ci = 0; ci < 4; ++ci) {
                float a = (&gv.x)[ci];             // == full ascending-k sum
                a = __fmaf_rn(rr[ni][0], w1b[0][ci], a);
                a = __fmaf_rn(rr[ni][1], w1b[1][ci], a);
                a = __fmaf_rn(rr[ni][2], w1b[2][ci], a);
                a = fmaxf(a + bb[ci], 0.0f);
                (&hv.x)[ci] = (n < nvalid) ? a : 0.0f;
            }
            *(float4*)&gs[n][c0] = hv;             // in-place h1
        }
    }
    __syncthreads();

    // ======== phase 3: h2 = relu(h1 @ W2 + b2); masked max over n ==========
    // Channel-split (two 4-ch halves), 2-row W2 tile, float2 h1 reads; the
    // per-output FMA chain runs cc = 0..63 strictly ascending -> bit-exact.
    {
        const float (*h1)[68] = gs;
        const int c4 = (t & 15) * 4;
        const int nb = (t >> 4) * 4;
        #pragma unroll
        for (int half = 0; half < 2; ++half) {
            const int ch0 = half * 64 + c4;
            float acc[4][4];
            #pragma unroll
            for (int ni = 0; ni < 4; ++ni)
                #pragma unroll
                for (int k = 0; k < 4; ++k) acc[ni][k] = 0.0f;

            #pragma unroll 2
            for (int ccb = 0; ccb < 16; ++ccb) {
                #pragma unroll
                for (int pr = 0; pr < 2; ++pr) {   // cc = ccb*4 + pr*2 + {0,1}
                    const int cc0 = ccb * 4 + pr * 2;
                    const float4 wt0 = *(const float4*)&W2[(cc0 + 0) * 128 + ch0];
                    const float4 wt1 = *(const float4*)&W2[(cc0 + 1) * 128 + ch0];
                    #pragma unroll
                    for (int ni = 0; ni < 4; ++ni) {
                        const float2 av = *(const float2*)&h1[nb + ni][cc0];
                        acc[ni][0] = __fmaf_rn(av.x, wt0.x, acc[ni][0]);
                        acc[ni][1] = __fmaf_rn(av.x, wt0.y, acc[ni][1]);
                        acc[ni][2] = __fmaf_rn(av.x, wt0.z, acc[ni][2]);
                        acc[ni][3] = __fmaf_rn(av.x, wt0.w, acc[ni][3]);
                        acc[ni][0] = __fmaf_rn(av.y, wt1.x, acc[ni][0]);
                        acc[ni][1] = __fmaf_rn(av.y, wt1.y, acc[ni][1]);
                        acc[ni][2] = __fmaf_rn(av.y, wt1.z, acc[ni][2]);
                        acc[ni][3] = __fmaf_rn(av.y, wt1.w, acc[ni][3]);
                    }
                }
            }
            float m4v[4];
            #pragma unroll
            for (int k = 0; k < 4; ++k) {
                const float bb = b2[ch0 + k];
                float mm = 0.0f;  // relu floor; valid set nonempty (self)
                #pragma unroll
                for (int ni = 0; ni < 4; ++ni)
                    if (nb + ni < nvalid) mm = fmaxf(mm, acc[ni][k] + bb);
                m4v[k] = mm;
            }
            #pragma unroll
            for (int k = 0; k < 4; ++k) {          // exact max-reduce over n-groups
                float v = m4v[k];
                v = fmaxf(v, __shfl_down(v, 32));
                v = fmaxf(v, __shfl_down(v, 16));
                m4v[k] = v;
            }
            if ((t & 63) < 16) {
                #pragma unroll
                for (int k = 0; k < 4; ++k) pmw[w][ch0 + k] = m4v[k];
            }
        }
    }
    __syncthreads();

    if (t < 128)
        aggS[t] = fmaxf(fmaxf(pmw[0][t], pmw[1][t]),
                        fmaxf(pmw[2][t], pmw[3][t]));
    __syncthreads();

    // ======== phase 4: out[i][t] = relu(aggS . Wg[:,t] + bg[t]) ============
    {
        float acc = 0.0f;
        #pragma unroll 8
        for (int k = 0; k < 128; ++k)
            acc = __fmaf_rn(aggS[k], Wg[k * 256 + t], acc);
        out[i * 256 + t] = fmaxf(acc + bg[t], 0.0f);
    }
}

// ---------------------------------------------------------------------------
extern "C" void kernel_launch(void* const* d_in, const int* in_sizes, int n_in,
                              void* d_out, int out_size, void* d_ws, size_t ws_size,
                              hipStream_t stream) {
    const float* x   = (const float*)d_in[0];
    const float* pos = (const float*)d_in[1];
    // d_in[2] = batch (all zeros) — unused
    const float* W1 = (const float*)d_in[3];
    const float* b1 = (const float*)d_in[4];
    const float* W2 = (const float*)d_in[5];
    const float* b2 = (const float*)d_in[6];
    const float* Wg = (const float*)d_in[7];
    const float* bg = (const float*)d_in[8];
    float* out = (float*)d_out;

    float* g = (float*)d_ws;   // 8192*64 floats = 2 MB, fully written by k_g

    k_g<<<N_PTS / 32, 256, 0, stream>>>(x, W1, g);
    k_sel<<<N_PTS, 256, 0, stream>>>(pos, out);
    k_mlp<<<N_PTS, 256, 0, stream>>>(g, pos, W1, b1, W2, b2, Wg, bg, out);
}

// Round 14
// 376.854 us; speedup vs baseline: 1.1845x; 1.0097x over previous
//
#include <hip/hip_runtime.h>

#define N_PTS 8192
#define R2F 0.015625f   // R*R, exactly representable

// ---------------- g = x @ W1a (NO bias; R16 chain verbatim, 32-row tiles) ---
__global__ __launch_bounds__(256) void k_g(const float* __restrict__ x,
                                           const float* __restrict__ W1,
                                           float* __restrict__ g) {
    __shared__ float xs[32][68];
    __shared__ float ws_[64][64];
    const int t = threadIdx.x;
    const int r0 = blockIdx.x * 32;
    for (int v = t; v < 1024; v += 256)
        ((float4*)&ws_[0][0])[v] = ((const float4*)W1)[v];   // W1 rows 0..63
    for (int v = t; v < 512; v += 256) {
        const int n = v >> 4, c4 = (v & 15) * 4;
        *(float4*)&xs[n][c4] = *(const float4*)&x[(r0 + n) * 64 + c4];
    }
    __syncthreads();
    const int c0 = (t & 15) * 4, n0 = (t >> 4) * 2;
    float acc[2][4];
    #pragma unroll
    for (int ni = 0; ni < 2; ++ni)
        #pragma unroll
        for (int ci = 0; ci < 4; ++ci) acc[ni][ci] = 0.0f;
    #pragma unroll
    for (int kb4 = 0; kb4 < 16; ++kb4) {
        float4 av[2], wv[4];
        #pragma unroll
        for (int ni = 0; ni < 2; ++ni)
            av[ni] = *(const float4*)&xs[n0 + ni][kb4 * 4];
        #pragma unroll
        for (int ki = 0; ki < 4; ++ki)
            wv[ki] = *(const float4*)&ws_[kb4 * 4 + ki][c0];
        #pragma unroll
        for (int ki = 0; ki < 4; ++ki) {           // k = 4*kb4 + ki, ascending
            #pragma unroll
            for (int ni = 0; ni < 2; ++ni) {
                const float a = (&av[ni].x)[ki];
                acc[ni][0] = __fmaf_rn(a, wv[ki].x, acc[ni][0]);
                acc[ni][1] = __fmaf_rn(a, wv[ki].y, acc[ni][1]);
                acc[ni][2] = __fmaf_rn(a, wv[ki].z, acc[ni][2]);
                acc[ni][3] = __fmaf_rn(a, wv[ki].w, acc[ni][3]);
            }
        }
    }
    #pragma unroll
    for (int ni = 0; ni < 2; ++ni)
        *(float4*)&g[(r0 + n0 + ni) * 64 + c0] =
            make_float4(acc[ni][0], acc[ni][1], acc[ni][2], acc[ni][3]);
}

// Bit-exact d2 key: shared by phase 1 and the rare rescan path. Identical
// intrinsic DAG (__fmul/__fadd/__fmaf/__fsub _rn) -> identical bits at both
// call sites (IEEE determinism; no reassociation possible on intrinsics).
__device__ __forceinline__ unsigned d2key(const float* __restrict__ pos, int j,
                                          float xi, float yi, float zi,
                                          float sqi) {
    const float xj = pos[j * 3 + 0], yj = pos[j * 3 + 1], zj = pos[j * 3 + 2];
    const float sqj = __fadd_rn(__fadd_rn(__fmul_rn(xj, xj), __fmul_rn(yj, yj)),
                                __fmul_rn(zj, zj));
    const float dot = __fmaf_rn(zi, zj, __fmaf_rn(yi, yj, __fmul_rn(xi, xj)));
    const float d2  = __fsub_rn(__fadd_rn(sqi, sqj), __fmul_rn(2.0f, dot));
    unsigned b = __float_as_uint(d2);
    return (b & 0x80000000u) ? ~b : (b | 0x80000000u);  // monotone total order
}

// ---------------- k_sel: neighbor selection only ----------------------------
// R11 lesson: (256,8) caps VGPR at 32; selection needs ~35 -> suspected spill
// (same failure mode as R4's (512,8)), consistent with k_sel ~165us vs the
// ~40us latency model. (256,6) caps at 42 -> headroom, 6 waves/SIMD.
// Output: 64 packed ushorts (j | valid<<15) in the first 128 B of the
// point's own out row (k_mlp block i reads then fully overwrites row i).
__global__ __launch_bounds__(256, 6) void k_sel(const float* __restrict__ pos,
                                                float* __restrict__ out) {
    __shared__ unsigned mb[4][64];
    __shared__ unsigned mj[4][64];

    const int t    = threadIdx.x;
    const int lane = t & 63;
    const int w    = t >> 6;         // wave id; owns quarter j in [2048w, 2048w+2048)
    const int qb   = w << 11;
    const int i    = blockIdx.x;

    const float xi = pos[i * 3 + 0], yi = pos[i * 3 + 1], zi = pos[i * 3 + 2];
    const float sqi = __fadd_rn(__fadd_rn(__fmul_rn(xi, xi), __fmul_rn(yi, yi)),
                                __fmul_rn(zi, zi));

    // ---- phase 1: d2 keys; track per-lane FOUR smallest (b, j) ----
    unsigned m1b = 0xFFFFFFFFu, m2b = 0xFFFFFFFFu,
             m3b = 0xFFFFFFFFu, m4b = 0xFFFFFFFFu;
    int      m1j = 0x7FFFFFFF,  m2j = 0x7FFFFFFF,
             m3j = 0x7FFFFFFF,  m4j = 0x7FFFFFFF;
    #pragma unroll
    for (int k = 0; k < 32; ++k) {
        const int j = qb + lane + (k << 6);
        const unsigned b = d2key(pos, j, xi, yi, zi, sqi);
        if (b < m1b) {
            m4b = m3b; m4j = m3j; m3b = m2b; m3j = m2j;
            m2b = m1b; m2j = m1j; m1b = b;   m1j = j;
        } else if (b < m2b) {
            m4b = m3b; m4j = m3j; m3b = m2b; m3j = m2j;
            m2b = b;   m2j = j;
        } else if (b < m3b) {
            m4b = m3b; m4j = m3j; m3b = b;   m3j = j;
        } else if (b < m4b) {
            m4b = b;   m4j = j;
        }
    }

    // unique ascending pads: no rank collisions in the merge (the R9 bug)
    mb[w][lane] = 0xFFFFFFFFu;
    mj[w][lane] = 0xFFFFFF00u | (unsigned)((w << 6) | lane);

    // ---- pops with early exit; lazy lane-min: m1->m2->m3->m4->rescan ----
    unsigned removed = 0u;
    int      level = 0;
    unsigned lb = m1b;
    int      lj = m1j;
    for (int s = 0; s < 64; ++s) {
        unsigned rb = lb;
        int      rj = lj;
        #pragma unroll
        for (int off = 32; off > 0; off >>= 1) {
            const unsigned ob = (unsigned)__shfl_down((int)rb, off);
            const int      oj = __shfl_down(rj, off);
            if (ob < rb || (ob == rb && oj < rj)) { rb = ob; rj = oj; }
        }
        const unsigned wb = (unsigned)__shfl((int)rb, 0);
        const int      wj = __shfl(rj, 0);
        const unsigned db = (wb & 0x80000000u) ? (wb ^ 0x80000000u) : ~wb;
        if (!(__uint_as_float(db) <= R2F)) break;   // wave-uniform; pops ascend
        if (lane == 0) { mb[w][s] = wb; mj[w][s] = (unsigned)wj; }
        if (lb == wb && lj == wj) {                 // unique owner lane
            removed |= 1u << ((wj - qb - lane) >> 6);
            ++level;
            if      (level == 1) { lb = m2b; lj = m2j; }
            else if (level == 2) { lb = m3b; lj = m3j; }
            else if (level == 3) { lb = m4b; lj = m4j; }
            else {                                  // rare: recompute rescan
                lb = 0xFFFFFFFFu; lj = 0x7FFFFFFF;
                #pragma unroll 4
                for (int k = 0; k < 32; ++k) {
                    if (!(removed & (1u << k))) {
                        const int jr = qb + lane + (k << 6);
                        const unsigned b = d2key(pos, jr, xi, yi, zi, sqi);
                        if (b < lb) { lb = b; lj = jr; }  // j asc: ties keep incumbent
                    }
                }
            }
        }
    }
    __syncthreads();

    {   // merge: exact global top-64 by (b, j) via parallel rank (bijective)
        const int p = lane;
        const unsigned be = mb[w][p];
        const unsigned je = mj[w][p];
        int rank = p;
        #pragma unroll
        for (int d = 1; d < 4; ++d) {
            const int wp = (w + d) & 3;
            int lo = 0;
            #pragma unroll
            for (int st = 32; st > 0; st >>= 1) {
                const int idx = lo + st - 1;
                const unsigned ob = mb[wp][idx];
                const unsigned oj = mj[wp][idx];
                if (ob < be || (ob == be && oj < je)) lo += st;
            }
            {
                const unsigned ob = mb[wp][lo];
                const unsigned oj = mj[wp][lo];
                if (ob < be || (ob == be && oj < je)) lo += 1;
            }
            rank += lo;
        }
        if (rank < 64) {
            const unsigned db = (be & 0x80000000u) ? (be ^ 0x80000000u) : ~be;
            const bool ok = (__uint_as_float(db) <= R2F);  // pads decode NaN -> false
            ((ushort*)(out + (size_t)i * 256))[rank] =
                (ushort)((je & 8191u) | (ok ? 0x8000u : 0u));
        }
    }
}

// ---------------- k_mlp: gather + MLP + max-agg + global_nn -----------------
// Phases 2-4 byte-identical to the R10-passed kernel. R11: VGPR=40 but
// (256,5) bound itself capped occupancy at 5 waves/SIMD; (256,6) caps regs
// at 42 >= 40 used -> 6th wave unlocked.
__global__ __launch_bounds__(256, 6) void k_mlp(const float* __restrict__ g,
                                                const float* __restrict__ pos,
                                                const float* __restrict__ W1,
                                                const float* __restrict__ b1,
                                                const float* __restrict__ W2,
                                                const float* __restrict__ b2,
                                                const float* __restrict__ Wg,
                                                const float* __restrict__ bg,
                                                float* __restrict__ out) {
    __shared__ float gs[64][68];     // 17408 B
    __shared__ float pmw[4][128];    // 2 KB
    __shared__ float aggS[128];
    __shared__ int   selj[64];
    __shared__ int   nvalidS;

    const int t = threadIdx.x;
    const int w = t >> 6;
    const int i = blockIdx.x;

    const float xi = pos[i * 3 + 0], yi = pos[i * 3 + 1], zi = pos[i * 3 + 2];

    bool ok = false;
    if (t < 64) {   // wave 0 reads the packed selection from its own out row
        const unsigned sv = ((const ushort*)(out + (size_t)i * 256))[t];
        selj[t] = (int)(sv & 8191u);
        ok = (sv & 0x8000u) != 0u;
    }
    __syncthreads();   // selj visible to all

    // ======== gather g rows; nvalid ballot (wave 0) ========================
    for (int v = t; v < 1024; v += 256) {
        const int n = v >> 4, c4 = (v & 15) * 4;   // rows >= nvalid never used
        *(float4*)&gs[n][c4] = *(const float4*)&g[selj[n] * 64 + c4];
    }
    {
        const unsigned long long vm = __ballot(ok);
        if (t == 0) nvalidS = __popcll(vm);        // asc d2 -> popcount == prefix
    }
    __syncthreads();
    const int nvalid = nvalidS;

    // ======== phase 2: h1 = relu(g + rel @ W1b + b1), IN PLACE over gs ======
    {
        const int c0 = (t & 15) * 4, n0 = (t >> 4) * 4;
        float rr[4][3];
        #pragma unroll
        for (int ni = 0; ni < 4; ++ni) {
            const int j = selj[n0 + ni];
            rr[ni][0] = pos[j * 3 + 0] - xi;
            rr[ni][1] = pos[j * 3 + 1] - yi;
            rr[ni][2] = pos[j * 3 + 2] - zi;
        }
        float w1b[3][4], bb[4];
        #pragma unroll
        for (int ci = 0; ci < 4; ++ci) {
            w1b[0][ci] = W1[4096 + c0 + ci];
            w1b[1][ci] = W1[4160 + c0 + ci];
            w1b[2][ci] = W1[4224 + c0 + ci];
            bb[ci]     = b1[c0 + ci];
        }
        #pragma unroll
        for (int ni = 0; ni < 4; ++ni) {
            const int n = n0 + ni;
            const float4 gv = *(const float4*)&gs[n][c0];
            float4 hv;
            #pragma unroll
            for (int ci = 0; ci < 4; ++ci) {
                float a = (&gv.x)[ci];             // == full ascending-k sum
                a = __fmaf_rn(rr[ni][0], w1b[0][ci], a);
                a = __fmaf_rn(rr[ni][1], w1b[1][ci], a);
                a = __fmaf_rn(rr[ni][2], w1b[2][ci], a);
                a = fmaxf(a + bb[ci], 0.0f);
                (&hv.x)[ci] = (n < nvalid) ? a : 0.0f;
            }
            *(float4*)&gs[n][c0] = hv;             // in-place h1
        }
    }
    __syncthreads();

    // ======== phase 3: h2 = relu(h1 @ W2 + b2); masked max over n ==========
    // Channel-split (two 4-ch halves), 2-row W2 tile, float2 h1 reads; the
    // per-output FMA chain runs cc = 0..63 strictly ascending -> bit-exact.
    {
        const float (*h1)[68] = gs;
        const int c4 = (t & 15) * 4;
        const int nb = (t >> 4) * 4;
        #pragma unroll
        for (int half = 0; half < 2; ++half) {
            const int ch0 = half * 64 + c4;
            float acc[4][4];
            #pragma unroll
            for (int ni = 0; ni < 4; ++ni)
                #pragma unroll
                for (int k = 0; k < 4; ++k) acc[ni][k] = 0.0f;

            #pragma unroll 2
            for (int ccb = 0; ccb < 16; ++ccb) {
                #pragma unroll
                for (int pr = 0; pr < 2; ++pr) {   // cc = ccb*4 + pr*2 + {0,1}
                    const int cc0 = ccb * 4 + pr * 2;
                    const float4 wt0 = *(const float4*)&W2[(cc0 + 0) * 128 + ch0];
                    const float4 wt1 = *(const float4*)&W2[(cc0 + 1) * 128 + ch0];
                    #pragma unroll
                    for (int ni = 0; ni < 4; ++ni) {
                        const float2 av = *(const float2*)&h1[nb + ni][cc0];
                        acc[ni][0] = __fmaf_rn(av.x, wt0.x, acc[ni][0]);
                        acc[ni][1] = __fmaf_rn(av.x, wt0.y, acc[ni][1]);
                        acc[ni][2] = __fmaf_rn(av.x, wt0.z, acc[ni][2]);
                        acc[ni][3] = __fmaf_rn(av.x, wt0.w, acc[ni][3]);
                        acc[ni][0] = __fmaf_rn(av.y, wt1.x, acc[ni][0]);
                        acc[ni][1] = __fmaf_rn(av.y, wt1.y, acc[ni][1]);
                        acc[ni][2] = __fmaf_rn(av.y, wt1.z, acc[ni][2]);
                        acc[ni][3] = __fmaf_rn(av.y, wt1.w, acc[ni][3]);
                    }
                }
            }
            float m4v[4];
            #pragma unroll
            for (int k = 0; k < 4; ++k) {
                const float bb = b2[ch0 + k];
                float mm = 0.0f;  // relu floor; valid set nonempty (self)
                #pragma unroll
                for (int ni = 0; ni < 4; ++ni)
                    if (nb + ni < nvalid) mm = fmaxf(mm, acc[ni][k] + bb);
                m4v[k] = mm;
            }
            #pragma unroll
            for (int k = 0; k < 4; ++k) {          // exact max-reduce over n-groups
                float v = m4v[k];
                v = fmaxf(v, __shfl_down(v, 32));
                v = fmaxf(v, __shfl_down(v, 16));
                m4v[k] = v;
            }
            if ((t & 63) < 16) {
                #pragma unroll
                for (int k = 0; k < 4; ++k) pmw[w][ch0 + k] = m4v[k];
            }
        }
    }
    __syncthreads();

    if (t < 128)
        aggS[t] = fmaxf(fmaxf(pmw[0][t], pmw[1][t]),
                        fmaxf(pmw[2][t], pmw[3][t]));
    __syncthreads();

    // ======== phase 4: out[i][t] = relu(aggS . Wg[:,t] + bg[t]) ============
    {
        float acc = 0.0f;
        #pragma unroll 8
        for (int k = 0; k < 128; ++k)
            acc = __fmaf_rn(aggS[k], Wg[k * 256 + t], acc);
        out[i * 256 + t] = fmaxf(acc + bg[t], 0.0f);
    }
}

// ---------------------------------------------------------------------------
extern "C" void kernel_launch(void* const* d_in, const int* in_sizes, int n_in,
                              void* d_out, int out_size, void* d_ws, size_t ws_size,
                              hipStream_t stream) {
    const float* x   = (const float*)d_in[0];
    const float* pos = (const float*)d_in[1];
    // d_in[2] = batch (all zeros) — unused
    const float* W1 = (const float*)d_in[3];
    const float* b1 = (const float*)d_in[4];
    const float* W2 = (const float*)d_in[5];
    const float* b2 = (const float*)d_in[6];
    const float* Wg = (const float*)d_in[7];
    const float* bg = (const float*)d_in[8];
    float* out = (float*)d_out;

    float* g = (float*)d_ws;   // 8192*64 floats = 2 MB, fully written by k_g

    k_g<<<N_PTS / 32, 256, 0, stream>>>(x, W1, g);
    k_sel<<<N_PTS, 256, 0, stream>>>(pos, out);
    k_mlp<<<N_PTS, 256, 0, stream>>>(g, pos, W1, b1, W2, b2, Wg, bg, out);
}